// Round 1
// baseline (239.565 us; speedup 1.0000x reference)
//
#include <hip/hip_runtime.h>

// CASSI forward A^T(A(x)) — register-resident per-dispersed-column formulation.
//
// out[b,l,m,n] = phi[l,m,n] * y2[b,m,n+2l]
// y2[b,m,c]    = sum_l phi[l,m,c-2l] * x[b,l,m,c-2l]   (valid 0<=c-2l<N)
//
// One thread per (b, m, c). c = n+2l is bijective in (l,n), so the thread
// reads each contributing x/phi once (phase 1), keeps the 28 phi values in
// registers, and writes each output consuming y2[c] once (phase 2).
// No LDS, no syncthreads, no atomics. All global accesses coalesced
// (fixed l => contiguous n across lanes).

constexpr int L_BANDS = 28;
constexpr int M_DIM   = 256;
constexpr int N_DIM   = 256;
constexpr int SHIFT   = 2;
constexpr int N_OUT   = N_DIM + SHIFT * (L_BANDS - 1);  // 310
constexpr int MN      = M_DIM * N_DIM;                  // 65536

__global__ __launch_bounds__(320) void cassi_fwd_kernel(
    const float* __restrict__ x,
    const float* __restrict__ phi,
    float* __restrict__ out)
{
    const int c = threadIdx.x;          // dispersed column this thread owns
    if (c >= N_OUT) return;             // threads 310..319 idle (no barrier below)

    const int bm = blockIdx.x;          // b*M + m
    const int b  = bm >> 8;             // M_DIM == 256
    const int m  = bm & (M_DIM - 1);

    const float* xb = x   + b * (L_BANDS * MN) + m * N_DIM;  // x[b, 0, m, 0]
    const float* pb = phi +                      m * N_DIM;  // phi[0, m, 0]
    float*       ob = out + b * (L_BANDS * MN) + m * N_DIM;  // out[b, 0, m, 0]

    float pr[L_BANDS];
    float acc = 0.0f;

    // Phase 1: gather -> y2[b,m,c] in register; cache phi values.
    #pragma unroll
    for (int l = 0; l < L_BANDS; ++l) {
        const int n = c - SHIFT * l;
        if (n >= 0 && n < N_DIM) {
            const float pv = pb[l * MN + n];
            pr[l] = pv;
            acc += xb[l * MN + n] * pv;
        } else {
            pr[l] = 0.0f;
        }
    }

    // Phase 2: scatter y2[c] to every output element that consumes it.
    #pragma unroll
    for (int l = 0; l < L_BANDS; ++l) {
        const int n = c - SHIFT * l;
        if (n >= 0 && n < N_DIM) {
            ob[l * MN + n] = pr[l] * acc;
        }
    }
}

extern "C" void kernel_launch(void* const* d_in, const int* in_sizes, int n_in,
                              void* d_out, int out_size, void* d_ws, size_t ws_size,
                              hipStream_t stream) {
    const float* x   = (const float*)d_in[0];
    const float* phi = (const float*)d_in[1];
    float*       out = (float*)d_out;

    const int B = in_sizes[0] / (L_BANDS * MN);   // 32

    dim3 grid(B * M_DIM);   // one block per (b, m) row: 8192 blocks
    dim3 block(320);        // 310 active threads (one per dispersed column)
    cassi_fwd_kernel<<<grid, block, 0, stream>>>(x, phi, out);
}

// Round 2
// 100.320 us; speedup vs baseline: 2.3880x; 2.3880x over previous
//
#include <hip/hip_runtime.h>

// CASSI forward A^T(A(x)) — register-resident per-dispersed-column formulation.
//
// out[b,l,m,n] = phi[l,m,n] * y2[b,m,n+2l]
// y2[b,m,c]    = sum_l phi[l,m,c-2l] * x[b,l,m,c-2l]   (valid 0<=c-2l<N)
//
// One thread per (b, m, c). c = n+2l is bijective in (l,n): the thread reads
// each contributing x/phi element exactly once, keeps phi in registers, and
// writes each output consuming y2[c] exactly once. No LDS, no atomics.
//
// R1 change vs R0: phase 1 split into (a) load-all then (b) FMA-all, with x
// values landing in a dedicated register array. R0's fused loop left only
// ~6 spare VGPRs (VGPR_Count=44), so loads issued in tiny batches and the
// kernel was latency-bound at 17% HBM BW. Separate arrays force all 56 loads
// into flight per wave (~14 KB) before the first s_waitcnt.

constexpr int L_BANDS = 28;
constexpr int M_DIM   = 256;
constexpr int N_DIM   = 256;
constexpr int SHIFT   = 2;
constexpr int N_OUT   = N_DIM + SHIFT * (L_BANDS - 1);  // 310
constexpr int MN      = M_DIM * N_DIM;                  // 65536

__global__ __launch_bounds__(320) void cassi_fwd_kernel(
    const float* __restrict__ x,
    const float* __restrict__ phi,
    float* __restrict__ out)
{
    const int c = threadIdx.x;          // dispersed column this thread owns
    if (c >= N_OUT) return;             // threads 310..319 idle (no barrier used)

    const int bm = blockIdx.x;          // b*M + m
    const int b  = bm >> 8;             // M_DIM == 256
    const int m  = bm & (M_DIM - 1);

    const float* xb = x   + b * (L_BANDS * MN) + m * N_DIM;  // x[b, 0, m, 0]
    const float* pb = phi +                      m * N_DIM;  // phi[0, m, 0]
    float*       ob = out + b * (L_BANDS * MN) + m * N_DIM;  // out[b, 0, m, 0]

    float xr[L_BANDS];
    float pr[L_BANDS];

    // Phase 1a: issue ALL loads (56 dwords/thread) before any consumption.
    #pragma unroll
    for (int l = 0; l < L_BANDS; ++l) {
        const int n = c - SHIFT * l;
        const bool v = (unsigned)n < (unsigned)N_DIM;
        xr[l] = v ? xb[l * MN + n] : 0.0f;
        pr[l] = v ? pb[l * MN + n] : 0.0f;
    }

    // Phase 1b: reduce to y2[b,m,c].
    float acc = 0.0f;
    #pragma unroll
    for (int l = 0; l < L_BANDS; ++l) {
        acc += xr[l] * pr[l];
    }

    // Phase 2: scatter y2[c] to every output element that consumes it.
    #pragma unroll
    for (int l = 0; l < L_BANDS; ++l) {
        const int n = c - SHIFT * l;
        if ((unsigned)n < (unsigned)N_DIM) {
            ob[l * MN + n] = pr[l] * acc;
        }
    }
}

extern "C" void kernel_launch(void* const* d_in, const int* in_sizes, int n_in,
                              void* d_out, int out_size, void* d_ws, size_t ws_size,
                              hipStream_t stream) {
    const float* x   = (const float*)d_in[0];
    const float* phi = (const float*)d_in[1];
    float*       out = (float*)d_out;

    const int B = in_sizes[0] / (L_BANDS * MN);   // 32

    dim3 grid(B * M_DIM);   // one block per (b, m) row: 8192 blocks
    dim3 block(320);        // 310 active threads (one per dispersed column)
    cassi_fwd_kernel<<<grid, block, 0, stream>>>(x, phi, out);
}

// Round 3
// 80.988 us; speedup vs baseline: 2.9580x; 1.2387x over previous
//
#include <hip/hip_runtime.h>

// CASSI forward A^T(A(x)) — register-resident per-dispersed-column formulation,
// pair-vectorized (float2).
//
// out[b,l,m,n] = phi[l,m,n] * y2[b,m,n+2l]
// y2[b,m,c]    = sum_l phi[l,m,c-2l] * x[b,l,m,c-2l]   (valid 0<=c-2l<N)
//
// c and n = c-2l share parity, so a thread owning columns {c0, c0+1} (c0 even)
// accesses {n0, n0+1} (n0 even) for every band: aligned 8B float2 loads/stores,
// and pair validity is uniform (n0 in [0,254]). Halves VMEM instruction count
// vs R1's scalar version at identical HBM traffic.
//
// out is write-once/never-read -> nontemporal stores keep x L3-resident
// (R1: FETCH 139MB of 235MB showed x partially cached; don't thrash it).

constexpr int L_BANDS = 28;
constexpr int M_DIM   = 256;
constexpr int N_DIM   = 256;
constexpr int SHIFT   = 2;
constexpr int N_OUT   = N_DIM + SHIFT * (L_BANDS - 1);  // 310
constexpr int NPAIR   = N_OUT / 2;                      // 155 column-pairs
constexpr int MN      = M_DIM * N_DIM;                  // 65536

typedef float v2f __attribute__((ext_vector_type(2)));

__global__ __launch_bounds__(320) void cassi_fwd_kernel(
    const float* __restrict__ x,
    const float* __restrict__ phi,
    float* __restrict__ out)
{
    const int t = threadIdx.x;
    const int r = (t >= 160) ? 1 : 0;   // which of the block's two m-rows
    const int p = t - 160 * r;          // pair index within the row
    if (p >= NPAIR) return;             // 5 idle lanes per half (no barriers)

    const int b  = blockIdx.x >> 7;                 // / (M_DIM/2)
    const int m  = ((blockIdx.x & 127) << 1) + r;   // 2*(blk%128) + r
    const int c0 = p << 1;                          // even dispersed column

    const float* xb = x   + b * (L_BANDS * MN) + m * N_DIM;  // x[b, 0, m, 0]
    const float* pb = phi +                      m * N_DIM;  // phi[0, m, 0]
    float*       ob = out + b * (L_BANDS * MN) + m * N_DIM;  // out[b, 0, m, 0]

    v2f xr[L_BANDS];
    v2f pr[L_BANDS];

    // Phase 1a: issue ALL loads (56 x 8B per thread) before any consumption.
    #pragma unroll
    for (int l = 0; l < L_BANDS; ++l) {
        const int n0 = c0 - SHIFT * l;                  // even
        const bool v = (unsigned)n0 < (unsigned)(N_DIM - 1);
        if (v) {
            xr[l] = *(const v2f*)(xb + l * MN + n0);
            pr[l] = *(const v2f*)(pb + l * MN + n0);
        } else {
            xr[l] = (v2f)(0.0f);
            pr[l] = (v2f)(0.0f);
        }
    }

    // Phase 1b: reduce to y2[b,m,c0] / y2[b,m,c0+1].
    v2f acc = (v2f)(0.0f);
    #pragma unroll
    for (int l = 0; l < L_BANDS; ++l) {
        acc += xr[l] * pr[l];
    }

    // Phase 2: scatter y2 to every output element that consumes it.
    #pragma unroll
    for (int l = 0; l < L_BANDS; ++l) {
        const int n0 = c0 - SHIFT * l;
        if ((unsigned)n0 < (unsigned)(N_DIM - 1)) {
            v2f o = pr[l] * acc;
            __builtin_nontemporal_store(o, (v2f*)(ob + l * MN + n0));
        }
    }
}

extern "C" void kernel_launch(void* const* d_in, const int* in_sizes, int n_in,
                              void* d_out, int out_size, void* d_ws, size_t ws_size,
                              hipStream_t stream) {
    const float* x   = (const float*)d_in[0];
    const float* phi = (const float*)d_in[1];
    float*       out = (float*)d_out;

    const int B = in_sizes[0] / (L_BANDS * MN);   // 32

    dim3 grid(B * (M_DIM / 2));  // one block per (b, m-pair): 4096 blocks
    dim3 block(320);             // 2 rows x 155 active pair-threads
    cassi_fwd_kernel<<<grid, block, 0, stream>>>(x, phi, out);
}